// Round 6
// baseline (58.371 us; speedup 1.0000x reference)
//
#include <hip/hip_runtime.h>

#define N 4096
#define LOG2E 1.4426950408889634f

__device__ __forceinline__ float fast_exp2(float x) {
#if __has_builtin(__builtin_amdgcn_exp2f)
    return __builtin_amdgcn_exp2f(x);
#else
    return exp2f(x);
#endif
}

__device__ float block_reduce_sum(float v) {
    __shared__ float red[8];
    int lane = threadIdx.x & 63;
    int wid = threadIdx.x >> 6;
    #pragma unroll
    for (int off = 32; off; off >>= 1) v += __shfl_down(v, off, 64);
    if (lane == 0) red[wid] = v;
    __syncthreads();
    if (threadIdx.x == 0) {
        int nw = (int)(blockDim.x >> 6);
        float s = red[0];
        for (int w = 1; w < nw; ++w) s += red[w];
        red[0] = s;
    }
    __syncthreads();
    float r = red[0];
    __syncthreads();
    return r;
}

// K1: per-vector stats + coefficient arrays.
// xa[vec][j] = (x_j, a_j)   (j-side, a = c1*x^2)
// ma[vec][i] = (m_i, a_i)   (i-side, m = -2*c1*x)
__global__ void k_stats(const float* __restrict__ fused,
                        const float* __restrict__ s1,
                        const float* __restrict__ s2,
                        float2* __restrict__ xa,
                        float2* __restrict__ ma) {
    int vec = blockIdx.x;
    int b = vec / 3, k = vec % 3;
    const float* src = (k == 0 ? fused : (k == 1 ? s1 : s2)) + b * 16384;
    int tid = threadIdx.x;
    float v[16];
    float s = 0.f;
    #pragma unroll
    for (int t = 0; t < 16; ++t) { v[t] = src[tid + t * 256]; s += v[t]; }
    float total = block_reduce_sum(s);
    float mean = total * (1.0f / 4096.0f);
    float ssq = 0.f;
    #pragma unroll
    for (int t = 0; t < 16; ++t) { float d = v[t] - mean; ssq += d * d; }
    float tssq = block_reduce_sum(ssq);
    float stdv = sqrtf(tssq / 4095.0f);            // ddof=1
    float sigma = fminf(fmaxf(0.2f * stdv, 0.001f), 1.0f);
    float inv = 1.0f / (stdv + 1e-8f);
    float c1 = -0.5f * LOG2E / (sigma * sigma);
    float2* xav = xa + (size_t)vec * N;
    float2* mav = ma + (size_t)vec * N;
    #pragma unroll
    for (int t = 0; t < 16; ++t) {
        int i = tid + t * 256;
        float x = (v[t] - mean) * inv;
        float a = c1 * x * x;
        xav[i] = make_float2(x, a);
        mav[i] = make_float2(-2.0f * c1 * x, a);
    }
}

// K2: raw kernel-sum partials. LDS-staged j-tiles, deep-ILP inner loop
// (2-j manual unroll x 4 i's = 8 independent exp streams, x unroll 2 = 16).
// Tasks t=0..9: t=b*5+p; p<3 marginal of vec b*3+p, p=3: joint(x,y1), p=4: joint(x,y2).
// Each thread owns IB=4 i-values (block covers 1024 i's, nib=4).
// grid = 10 * 4 * js, block 256.
__global__ void __launch_bounds__(256, 8)
k_pdf(const float2* __restrict__ xa,
      const float2* __restrict__ ma,
      float* __restrict__ part, int js) {
    __shared__ float2 sm2[128];   // marginal: (x_j, a_j)
    __shared__ float4 sm4[128];   // joint:    (x_j, y_j, S_j, -)
    const int nib = 4;
    int bid = blockIdx.x;
    int t = bid / (nib * js);
    int rem = bid % (nib * js);
    int ib = rem / js, jsp = rem % js;
    int p = t % 5, b = t / 5;
    int jlen = N / js;
    int j0 = jsp * jlen;
    int tid = threadIdx.x;
    int ibase = ib * 1024 + tid;

    float acc[4] = {0.f, 0.f, 0.f, 0.f};

    if (p < 3) {
        int v = b * 3 + p;
        const float2* xav = xa + (size_t)v * N;
        const float2* mav = ma + (size_t)v * N;
        float m[4], ai[4];
        #pragma unroll
        for (int u = 0; u < 4; ++u) {
            float2 q = mav[ibase + u * 256];
            m[u] = q.x; ai[u] = q.y;
        }
        for (int jt = 0; jt < jlen; jt += 128) {
            int cnt = min(128, jlen - jt);
            __syncthreads();
            if (tid < cnt) sm2[tid] = xav[j0 + jt + tid];
            __syncthreads();
            #pragma unroll 2
            for (int j = 0; j < cnt; j += 2) {
                float2 xj0 = sm2[j];
                float2 xj1 = sm2[j + 1];
                float e0[4], e1[4], f0[4], f1[4];
                #pragma unroll
                for (int u = 0; u < 4; ++u) {
                    e0[u] = fmaf(m[u], xj0.x, ai[u]) + xj0.y;
                    e1[u] = fmaf(m[u], xj1.x, ai[u]) + xj1.y;
                }
                #pragma unroll
                for (int u = 0; u < 4; ++u) {
                    f0[u] = fast_exp2(e0[u]);
                    f1[u] = fast_exp2(e1[u]);
                }
                #pragma unroll
                for (int u = 0; u < 4; ++u)
                    acc[u] += (f0[u] + f1[u]);
            }
        }
    } else {
        int vx = b * 3, vy = b * 3 + (p - 2);
        const float2* xav = xa + (size_t)vx * N;
        const float2* yav = xa + (size_t)vy * N;
        const float2* mxv = ma + (size_t)vx * N;
        const float2* myv = ma + (size_t)vy * N;
        float mx[4], my[4], C[4];
        #pragma unroll
        for (int u = 0; u < 4; ++u) {
            float2 qx = mxv[ibase + u * 256];
            float2 qy = myv[ibase + u * 256];
            mx[u] = qx.x; my[u] = qy.x; C[u] = qx.y + qy.y;
        }
        for (int jt = 0; jt < jlen; jt += 128) {
            int cnt = min(128, jlen - jt);
            __syncthreads();
            if (tid < cnt) {
                float2 xq = xav[j0 + jt + tid];
                float2 yq = yav[j0 + jt + tid];
                sm4[tid] = make_float4(xq.x, yq.x, xq.y + yq.y, 0.f);
            }
            __syncthreads();
            #pragma unroll 2
            for (int j = 0; j < cnt; j += 2) {
                float4 q0 = sm4[j];
                float4 q1 = sm4[j + 1];
                float e0[4], e1[4], f0[4], f1[4];
                #pragma unroll
                for (int u = 0; u < 4; ++u) {
                    e0[u] = fmaf(my[u], q0.y, fmaf(mx[u], q0.x, C[u])) + q0.z;
                    e1[u] = fmaf(my[u], q1.y, fmaf(mx[u], q1.x, C[u])) + q1.z;
                }
                #pragma unroll
                for (int u = 0; u < 4; ++u) {
                    f0[u] = fast_exp2(e0[u]);
                    f1[u] = fast_exp2(e1[u]);
                }
                #pragma unroll
                for (int u = 0; u < 4; ++u)
                    acc[u] += (f0[u] + f1[u]);
            }
        }
    }
    float* dst = part + ((size_t)t * js + jsp) * N + ibase;
    dst[0]   = acc[0];
    dst[256] = acc[1];
    dst[512] = acc[2];
    dst[768] = acc[3];
}

// K3a: reduce j-split partials -> pdf (/N) + per-(task,chunk) partial sums.
// grid = 10 * 16 blocks; block handles one 256-wide i-chunk of one task.
__global__ void k_reduce(const float* __restrict__ part, float* __restrict__ pdf,
                         float* __restrict__ sums_part, int js) {
    int blk = blockIdx.x;
    int t = blk >> 4;
    int ib = blk & 15;
    int i = ib * 256 + threadIdx.x;
    float s = 0.f;
    for (int q = 0; q < js; ++q) s += part[((size_t)t * js + q) * N + i];
    s *= (1.0f / N);
    pdf[(size_t)t * N + i] = s;
    float tot = block_reduce_sum(s);
    if (threadIdx.x == 0) sums_part[blk] = tot;
}

// K3b: per-(combo, i-chunk) MI partial. 64 blocks.
__global__ void k_mi2(const float* __restrict__ pdf,
                      const float* __restrict__ sums_part,
                      float* __restrict__ mi_part) {
    int blk = blockIdx.x;
    int c = blk >> 4;
    int ic = blk & 15;
    int b = c >> 1, pr = c & 1;
    int tj = b * 5 + 3 + pr;
    int tx = b * 5;
    int ty = b * 5 + 1 + pr;
    float sj = 0.f, sx = 0.f, sy = 0.f;
    #pragma unroll
    for (int q = 0; q < 16; ++q) {
        sj += sums_part[tj * 16 + q];
        sx += sums_part[tx * 16 + q];
        sy += sums_part[ty * 16 + q];
    }
    float inv_sj = 1.0f / (sj + 1e-10f);
    float inv_sx = 1.0f / (sx + 1e-10f);
    float inv_sy = 1.0f / (sy + 1e-10f);
    int i = ic * 256 + threadIdx.x;
    float pj = pdf[(size_t)tj * N + i] * inv_sj;
    float px = pdf[(size_t)tx * N + i] * inv_sx;
    float py = pdf[(size_t)ty * N + i] * inv_sy;
    float ratio = (pj + 1e-10f) / (px * py + 1e-10f);
    ratio = fminf(fmaxf(ratio, 1e-10f), 1e10f);
    float local = pj * __logf(ratio);
    float tot = block_reduce_sum(local);
    if (threadIdx.x == 0) mi_part[blk] = tot;
}

// K4: final. 1 block, 64 threads (1 wave).
__global__ void k_fin(const float* __restrict__ mi_part, float* __restrict__ out) {
    float v = mi_part[threadIdx.x];  // 64 entries
    #pragma unroll
    for (int off = 32; off; off >>= 1) v += __shfl_down(v, off, 64);
    if (threadIdx.x == 0) out[0] = -v * 0.5f;
}

extern "C" void kernel_launch(void* const* d_in, const int* in_sizes, int n_in,
                              void* d_out, int out_size, void* d_ws, size_t ws_size,
                              hipStream_t stream) {
    const float* fused = (const float*)d_in[0];
    const float* s1    = (const float*)d_in[1];
    const float* s2    = (const float*)d_in[2];
    float* out = (float*)d_out;
    float* ws  = (float*)d_ws;

    // ws layout (floats)
    const size_t off_xa   = 0;                         // 6*N*2
    const size_t off_ma   = off_xa + 12 * (size_t)N;   // 6*N*2
    const size_t off_pdf  = off_ma + 12 * (size_t)N;   // 10*N
    const size_t off_sp   = off_pdf + 10 * (size_t)N;  // 160
    const size_t off_mi   = off_sp + 160;              // 64
    const size_t off_part = off_mi + 64;               // 10*js*N

    int js = 64;
    while (js > 1 && (off_part + (size_t)10 * js * N) * 4 > ws_size) js >>= 1;

    float2* ws_xa   = (float2*)(ws + off_xa);
    float2* ws_ma   = (float2*)(ws + off_ma);
    float*  ws_pdf  = ws + off_pdf;
    float*  ws_sp   = ws + off_sp;
    float*  ws_mi   = ws + off_mi;
    float*  ws_part = ws + off_part;

    k_stats<<<dim3(6), dim3(256), 0, stream>>>(fused, s1, s2, ws_xa, ws_ma);
    k_pdf<<<dim3(10 * 4 * js), dim3(256), 0, stream>>>(ws_xa, ws_ma, ws_part, js);
    k_reduce<<<dim3(160), dim3(256), 0, stream>>>(ws_part, ws_pdf, ws_sp, js);
    k_mi2<<<dim3(64), dim3(256), 0, stream>>>(ws_pdf, ws_sp, ws_mi);
    k_fin<<<dim3(1), dim3(64), 0, stream>>>(ws_mi, out);
}

// Round 7
// 50.794 us; speedup vs baseline: 1.1492x; 1.1492x over previous
//
#include <hip/hip_runtime.h>

#define N 4096
#define NBIN 1024
#define LOG2E 1.4426950408889634f

__device__ __forceinline__ float fast_exp2(float x) {
#if __has_builtin(__builtin_amdgcn_exp2f)
    return __builtin_amdgcn_exp2f(x);
#else
    return exp2f(x);
#endif
}

__device__ float block_reduce_sum(float v) {
    __shared__ float red[8];
    int lane = threadIdx.x & 63;
    int wid = threadIdx.x >> 6;
    #pragma unroll
    for (int off = 32; off; off >>= 1) v += __shfl_down(v, off, 64);
    if (lane == 0) red[wid] = v;
    __syncthreads();
    if (threadIdx.x == 0) {
        int nw = (int)(blockDim.x >> 6);
        float s = red[0];
        for (int w = 1; w < nw; ++w) s += red[w];
        red[0] = s;
    }
    __syncthreads();
    float r = red[0];
    __syncthreads();
    return r;
}

__device__ float block_reduce_min(float v) {
    __shared__ float redm[8];
    int lane = threadIdx.x & 63;
    int wid = threadIdx.x >> 6;
    #pragma unroll
    for (int off = 32; off; off >>= 1) v = fminf(v, __shfl_down(v, off, 64));
    if (lane == 0) redm[wid] = v;
    __syncthreads();
    if (threadIdx.x == 0) {
        float s = redm[0];
        for (int w = 1; w < 4; ++w) s = fminf(s, redm[w]);
        redm[0] = s;
    }
    __syncthreads();
    float r = redm[0];
    __syncthreads();
    return r;
}

__device__ float block_reduce_max(float v) {
    __shared__ float redx[8];
    int lane = threadIdx.x & 63;
    int wid = threadIdx.x >> 6;
    #pragma unroll
    for (int off = 32; off; off >>= 1) v = fmaxf(v, __shfl_down(v, off, 64));
    if (lane == 0) redx[wid] = v;
    __syncthreads();
    if (threadIdx.x == 0) {
        float s = redx[0];
        for (int w = 1; w < 4; ++w) s = fmaxf(s, redx[w]);
        redx[0] = s;
    }
    __syncthreads();
    float r = redx[0];
    __syncthreads();
    return r;
}

// K1: per-vector stats + coefficient arrays + histogram params.
// xa[vec][j] = (x_j, a_j)   (a = c1*x^2, c1 in log2 units)
// ma[vec][i] = (m_i, a_i)   (m = -2*c1*x)
// par[vec*8 + {0:xmin, 1:inv_binw, 2:binw, 3:c1}]
__global__ void k_stats(const float* __restrict__ fused,
                        const float* __restrict__ s1,
                        const float* __restrict__ s2,
                        float2* __restrict__ xa,
                        float2* __restrict__ ma,
                        float* __restrict__ par) {
    int vec = blockIdx.x;
    int b = vec / 3, k = vec % 3;
    const float* src = (k == 0 ? fused : (k == 1 ? s1 : s2)) + b * 16384;
    int tid = threadIdx.x;
    float v[16];
    float s = 0.f;
    #pragma unroll
    for (int t = 0; t < 16; ++t) { v[t] = src[tid + t * 256]; s += v[t]; }
    float total = block_reduce_sum(s);
    float mean = total * (1.0f / 4096.0f);
    float ssq = 0.f;
    #pragma unroll
    for (int t = 0; t < 16; ++t) { float d = v[t] - mean; ssq += d * d; }
    float tssq = block_reduce_sum(ssq);
    float stdv = sqrtf(tssq / 4095.0f);            // ddof=1
    float sigma = fminf(fmaxf(0.2f * stdv, 0.001f), 1.0f);
    float inv = 1.0f / (stdv + 1e-8f);
    float c1 = -0.5f * LOG2E / (sigma * sigma);

    float x[16];
    float lmin = 1e30f, lmax = -1e30f;
    #pragma unroll
    for (int t = 0; t < 16; ++t) {
        x[t] = (v[t] - mean) * inv;
        lmin = fminf(lmin, x[t]);
        lmax = fmaxf(lmax, x[t]);
    }
    float xmin = block_reduce_min(lmin);
    float xmax = block_reduce_max(lmax);

    float2* xav = xa + (size_t)vec * N;
    float2* mav = ma + (size_t)vec * N;
    #pragma unroll
    for (int t = 0; t < 16; ++t) {
        int i = tid + t * 256;
        float a = c1 * x[t] * x[t];
        xav[i] = make_float2(x[t], a);
        mav[i] = make_float2(-2.0f * c1 * x[t], a);
    }
    if (tid == 0) {
        float range = fmaxf(xmax - xmin, 1e-6f);
        float binw = range * (1.0f / NBIN);
        par[vec * 8 + 0] = xmin;
        par[vec * 8 + 1] = (float)NBIN / range;
        par[vec * 8 + 2] = binw;
        par[vec * 8 + 3] = c1;
    }
}

// K2a: per-vector histogram (integer counts + fixed-point sums -> bin means).
// 6 blocks x 256. Fully deterministic (integer LDS atomics).
__global__ void k_hist(const float2* __restrict__ xa,
                       const float* __restrict__ par,
                       float* __restrict__ hcnt,
                       float* __restrict__ hmu) {
    __shared__ unsigned int cnt[NBIN];
    __shared__ int qs[NBIN];
    int vec = blockIdx.x;
    const float* P = par + vec * 8;
    float xmin = P[0], inv_bw = P[1], binw = P[2];
    int tid = threadIdx.x;
    for (int u = tid; u < NBIN; u += 256) { cnt[u] = 0u; qs[u] = 0; }
    __syncthreads();
    #pragma unroll
    for (int t = 0; t < 16; ++t) {
        float x = xa[(size_t)vec * N + tid + t * 256].x;
        float rel = x - xmin;
        int bb = min(NBIN - 1, max(0, (int)(rel * inv_bw)));
        atomicAdd(&cnt[bb], 1u);
        atomicAdd(&qs[bb], (int)rintf(rel * 16384.0f));
    }
    __syncthreads();
    for (int u = tid; u < NBIN; u += 256) {
        unsigned int c = cnt[u];
        hcnt[vec * NBIN + u] = (float)c;
        float mu = c ? xmin + ((float)qs[u] / (float)c) * (1.0f / 16384.0f)
                     : xmin + (u + 0.5f) * binw;
        hmu[vec * NBIN + u] = mu;
    }
}

// K2b: marginal pdf per point via windowed histogram sweep.
// grid = 6 vecs * 16 chunks = 96 blocks x 256 (1 point/thread).
__global__ void k_marg(const float2* __restrict__ xa,
                       const float* __restrict__ par,
                       const float* __restrict__ hcnt,
                       const float* __restrict__ hmu,
                       float* __restrict__ marg,
                       float* __restrict__ msum_part) {
    int blk = blockIdx.x;
    int vec = blk >> 4, ic = blk & 15;
    int i = ic * 256 + threadIdx.x;
    const float* P = par + vec * 8;
    float xmin = P[0], inv_bw = P[1], c1 = P[3];
    float xi = xa[(size_t)vec * N + i].x;
    float R = sqrtf(45.0f / fabsf(c1));      // exp2 cutoff at 2^-45
    int b0 = max(0, (int)((xi - R - xmin) * inv_bw));
    int b1 = min(NBIN - 1, (int)((xi + R - xmin) * inv_bw) + 1);
    const float* hc = hcnt + vec * NBIN;
    const float* hm = hmu + vec * NBIN;
    float acc = 0.f;
    #pragma unroll 4
    for (int bb = b0; bb <= b1; ++bb) {
        float d = xi - hm[bb];
        acc += hc[bb] * fast_exp2(c1 * d * d);
    }
    float raw = acc * (1.0f / N);
    marg[(size_t)vec * N + i] = raw;
    float tot = block_reduce_sum(raw);
    if (threadIdx.x == 0) msum_part[blk] = tot;
}

// K3: joint raw kernel sums (exact brute force). Tasks tt=0..3:
// b=tt>>1, pr=tt&1, vx=b*3, vy=b*3+1+pr.
// IB=4 i's/thread, LDS-staged j-tile; grid = 4 * 4 * js, block 256.
__global__ void __launch_bounds__(256, 8)
k_joint(const float2* __restrict__ xa,
        const float2* __restrict__ ma,
        float* __restrict__ part, int js) {
    __shared__ float4 sj[128];   // (x_j, y_j, S_j, -)
    const int nib = 4;
    int bid = blockIdx.x;
    int tt = bid / (nib * js);
    int rem = bid % (nib * js);
    int ib = rem / js, jsp = rem % js;
    int b = tt >> 1, pr = tt & 1;
    int vx = b * 3, vy = b * 3 + 1 + pr;
    int jlen = N / js;
    int j0 = jsp * jlen;
    int tid = threadIdx.x;
    int ibase = ib * 1024 + tid;

    const float2* xav = xa + (size_t)vx * N;
    const float2* yav = xa + (size_t)vy * N;
    const float2* mxv = ma + (size_t)vx * N;
    const float2* myv = ma + (size_t)vy * N;

    float mx[4], my[4], C[4];
    #pragma unroll
    for (int u = 0; u < 4; ++u) {
        float2 qx = mxv[ibase + u * 256];
        float2 qy = myv[ibase + u * 256];
        mx[u] = qx.x; my[u] = qy.x; C[u] = qx.y + qy.y;
    }
    float acc[4] = {0.f, 0.f, 0.f, 0.f};

    for (int jt = 0; jt < jlen; jt += 128) {
        int cnt = min(128, jlen - jt);
        __syncthreads();
        if (tid < cnt) {
            float2 xq = xav[j0 + jt + tid];
            float2 yq = yav[j0 + jt + tid];
            sj[tid] = make_float4(xq.x, yq.x, xq.y + yq.y, 0.f);
        }
        __syncthreads();
        #pragma unroll 2
        for (int j = 0; j < cnt; j += 2) {
            float4 q0 = sj[j];
            float4 q1 = sj[j + 1];
            float e0[4], e1[4], f0[4], f1[4];
            #pragma unroll
            for (int u = 0; u < 4; ++u) {
                e0[u] = fmaf(my[u], q0.y, fmaf(mx[u], q0.x, C[u])) + q0.z;
                e1[u] = fmaf(my[u], q1.y, fmaf(mx[u], q1.x, C[u])) + q1.z;
            }
            #pragma unroll
            for (int u = 0; u < 4; ++u) {
                f0[u] = fast_exp2(e0[u]);
                f1[u] = fast_exp2(e1[u]);
            }
            #pragma unroll
            for (int u = 0; u < 4; ++u)
                acc[u] += (f0[u] + f1[u]);
        }
    }
    float* dst = part + ((size_t)tt * js + jsp) * N + ibase;
    dst[0]   = acc[0];
    dst[256] = acc[1];
    dst[512] = acc[2];
    dst[768] = acc[3];
}

// K4: reduce joint j-split partials -> pdfj (/N) + per-(task,chunk) sums.
// grid = 4 * 16 = 64 blocks.
__global__ void k_reduce(const float* __restrict__ part, float* __restrict__ pdfj,
                         float* __restrict__ jsum_part, int js) {
    int blk = blockIdx.x;
    int tt = blk >> 4;
    int ic = blk & 15;
    int i = ic * 256 + threadIdx.x;
    float s = 0.f;
    #pragma unroll 4
    for (int q = 0; q < js; ++q) s += part[((size_t)tt * js + q) * N + i];
    s *= (1.0f / N);
    pdfj[(size_t)tt * N + i] = s;
    float tot = block_reduce_sum(s);
    if (threadIdx.x == 0) jsum_part[blk] = tot;
}

// K5: per-(combo, i-chunk) MI partial. 64 blocks.
__global__ void k_mi2(const float* __restrict__ pdfj,
                      const float* __restrict__ jsum_part,
                      const float* __restrict__ marg,
                      const float* __restrict__ msum_part,
                      float* __restrict__ mi_part) {
    int blk = blockIdx.x;
    int c = blk >> 4;
    int ic = blk & 15;
    int b = c >> 1, pr = c & 1;
    int vx = b * 3, vy = b * 3 + 1 + pr;
    float sj = 0.f, sx = 0.f, sy = 0.f;
    #pragma unroll
    for (int q = 0; q < 16; ++q) {
        sj += jsum_part[c * 16 + q];
        sx += msum_part[vx * 16 + q];
        sy += msum_part[vy * 16 + q];
    }
    float inv_sj = 1.0f / (sj + 1e-10f);
    float inv_sx = 1.0f / (sx + 1e-10f);
    float inv_sy = 1.0f / (sy + 1e-10f);
    int i = ic * 256 + threadIdx.x;
    float pj = pdfj[(size_t)c * N + i] * inv_sj;
    float px = marg[(size_t)vx * N + i] * inv_sx;
    float py = marg[(size_t)vy * N + i] * inv_sy;
    float ratio = (pj + 1e-10f) / (px * py + 1e-10f);
    ratio = fminf(fmaxf(ratio, 1e-10f), 1e10f);
    float local = pj * __logf(ratio);
    float tot = block_reduce_sum(local);
    if (threadIdx.x == 0) mi_part[blk] = tot;
}

// K6: final. 1 block, 64 threads (1 wave).
__global__ void k_fin(const float* __restrict__ mi_part, float* __restrict__ out) {
    float v = mi_part[threadIdx.x];  // 64 entries
    #pragma unroll
    for (int off = 32; off; off >>= 1) v += __shfl_down(v, off, 64);
    if (threadIdx.x == 0) out[0] = -v * 0.5f;
}

extern "C" void kernel_launch(void* const* d_in, const int* in_sizes, int n_in,
                              void* d_out, int out_size, void* d_ws, size_t ws_size,
                              hipStream_t stream) {
    const float* fused = (const float*)d_in[0];
    const float* s1    = (const float*)d_in[1];
    const float* s2    = (const float*)d_in[2];
    float* out = (float*)d_out;
    float* ws  = (float*)d_ws;

    // ws layout (floats)
    const size_t off_xa   = 0;                          // 6*N*2
    const size_t off_ma   = off_xa + 12 * (size_t)N;    // 6*N*2
    const size_t off_par  = off_ma + 12 * (size_t)N;    // 64
    const size_t off_hc   = off_par + 64;               // 6*NBIN
    const size_t off_hm   = off_hc + 6 * NBIN;          // 6*NBIN
    const size_t off_mg   = off_hm + 6 * NBIN;          // 6*N
    const size_t off_ms   = off_mg + 6 * (size_t)N;     // 96 (+pad)
    const size_t off_pj   = off_ms + 128;               // 4*N
    const size_t off_js   = off_pj + 4 * (size_t)N;     // 64
    const size_t off_mi   = off_js + 64;                // 64
    const size_t off_part = off_mi + 64;                // 4*js*N

    int js = 64;
    while (js > 1 && (off_part + (size_t)4 * js * N) * 4 > ws_size) js >>= 1;

    float2* ws_xa  = (float2*)(ws + off_xa);
    float2* ws_ma  = (float2*)(ws + off_ma);
    float*  ws_par = ws + off_par;
    float*  ws_hc  = ws + off_hc;
    float*  ws_hm  = ws + off_hm;
    float*  ws_mg  = ws + off_mg;
    float*  ws_ms  = ws + off_ms;
    float*  ws_pj  = ws + off_pj;
    float*  ws_js  = ws + off_js;
    float*  ws_mi  = ws + off_mi;
    float*  ws_part = ws + off_part;

    k_stats<<<dim3(6), dim3(256), 0, stream>>>(fused, s1, s2, ws_xa, ws_ma, ws_par);
    k_hist<<<dim3(6), dim3(256), 0, stream>>>(ws_xa, ws_par, ws_hc, ws_hm);
    k_marg<<<dim3(96), dim3(256), 0, stream>>>(ws_xa, ws_par, ws_hc, ws_hm, ws_mg, ws_ms);
    k_joint<<<dim3(4 * 4 * js), dim3(256), 0, stream>>>(ws_xa, ws_ma, ws_part, js);
    k_reduce<<<dim3(64), dim3(256), 0, stream>>>(ws_part, ws_pj, ws_js, js);
    k_mi2<<<dim3(64), dim3(256), 0, stream>>>(ws_pj, ws_js, ws_mg, ws_ms, ws_mi);
    k_fin<<<dim3(1), dim3(64), 0, stream>>>(ws_mi, out);
}

// Round 8
// 40.388 us; speedup vs baseline: 1.4453x; 1.2577x over previous
//
#include <hip/hip_runtime.h>

#define N 4096
#define NBIN 1024
#define LOG2E 1.4426950408889634f

__device__ __forceinline__ float fast_exp2(float x) {
#if __has_builtin(__builtin_amdgcn_exp2f)
    return __builtin_amdgcn_exp2f(x);
#else
    return exp2f(x);
#endif
}

__device__ float block_reduce_sum(float v) {
    __shared__ float red[16];
    int lane = threadIdx.x & 63;
    int wid = threadIdx.x >> 6;
    #pragma unroll
    for (int off = 32; off; off >>= 1) v += __shfl_down(v, off, 64);
    if (lane == 0) red[wid] = v;
    __syncthreads();
    if (threadIdx.x == 0) {
        int nw = (int)(blockDim.x >> 6);
        float s = red[0];
        for (int w = 1; w < nw; ++w) s += red[w];
        red[0] = s;
    }
    __syncthreads();
    float r = red[0];
    __syncthreads();
    return r;
}

__device__ float block_reduce_min(float v) {
    __shared__ float redm[16];
    int lane = threadIdx.x & 63;
    int wid = threadIdx.x >> 6;
    #pragma unroll
    for (int off = 32; off; off >>= 1) v = fminf(v, __shfl_down(v, off, 64));
    if (lane == 0) redm[wid] = v;
    __syncthreads();
    if (threadIdx.x == 0) {
        int nw = (int)(blockDim.x >> 6);
        float s = redm[0];
        for (int w = 1; w < nw; ++w) s = fminf(s, redm[w]);
        redm[0] = s;
    }
    __syncthreads();
    float r = redm[0];
    __syncthreads();
    return r;
}

__device__ float block_reduce_max(float v) {
    __shared__ float redx[16];
    int lane = threadIdx.x & 63;
    int wid = threadIdx.x >> 6;
    #pragma unroll
    for (int off = 32; off; off >>= 1) v = fmaxf(v, __shfl_down(v, off, 64));
    if (lane == 0) redx[wid] = v;
    __syncthreads();
    if (threadIdx.x == 0) {
        int nw = (int)(blockDim.x >> 6);
        float s = redx[0];
        for (int w = 1; w < nw; ++w) s = fmaxf(s, redx[w]);
        redx[0] = s;
    }
    __syncthreads();
    float r = redx[0];
    __syncthreads();
    return r;
}

// K1: per-vector stats + coefficient arrays + histogram (fused). 6 blocks x 256.
// xa[vec][j] = (x_j, a_j)   (a = c1*x^2, c1 in log2 units)
// ma[vec][i] = (m_i, a_i)   (m = -2*c1*x)
// par[vec*8 + {0:xmin, 1:inv_binw, 2:binw, 3:c1}]
// hcnt/hmu: per-bin count and mean (integer/fixed-point LDS atomics, deterministic).
__global__ void k_prep(const float* __restrict__ fused,
                       const float* __restrict__ s1,
                       const float* __restrict__ s2,
                       float2* __restrict__ xa,
                       float2* __restrict__ ma,
                       float* __restrict__ par,
                       float* __restrict__ hcnt,
                       float* __restrict__ hmu) {
    __shared__ unsigned int cnt[NBIN];
    __shared__ int qs[NBIN];
    int vec = blockIdx.x;
    int b = vec / 3, k = vec % 3;
    const float* src = (k == 0 ? fused : (k == 1 ? s1 : s2)) + b * 16384;
    int tid = threadIdx.x;
    float v[16];
    float s = 0.f;
    #pragma unroll
    for (int t = 0; t < 16; ++t) { v[t] = src[tid + t * 256]; s += v[t]; }
    float total = block_reduce_sum(s);
    float mean = total * (1.0f / 4096.0f);
    float ssq = 0.f;
    #pragma unroll
    for (int t = 0; t < 16; ++t) { float d = v[t] - mean; ssq += d * d; }
    float tssq = block_reduce_sum(ssq);
    float stdv = sqrtf(tssq / 4095.0f);            // ddof=1
    float sigma = fminf(fmaxf(0.2f * stdv, 0.001f), 1.0f);
    float inv = 1.0f / (stdv + 1e-8f);
    float c1 = -0.5f * LOG2E / (sigma * sigma);

    float x[16];
    float lmin = 1e30f, lmax = -1e30f;
    #pragma unroll
    for (int t = 0; t < 16; ++t) {
        x[t] = (v[t] - mean) * inv;
        lmin = fminf(lmin, x[t]);
        lmax = fmaxf(lmax, x[t]);
    }
    float xmin = block_reduce_min(lmin);
    float xmax = block_reduce_max(lmax);
    float range = fmaxf(xmax - xmin, 1e-6f);
    float inv_bw = (float)NBIN / range;
    float binw = range * (1.0f / NBIN);

    float2* xav = xa + (size_t)vec * N;
    float2* mav = ma + (size_t)vec * N;
    for (int u = tid; u < NBIN; u += 256) { cnt[u] = 0u; qs[u] = 0; }
    __syncthreads();
    #pragma unroll
    for (int t = 0; t < 16; ++t) {
        int i = tid + t * 256;
        float a = c1 * x[t] * x[t];
        xav[i] = make_float2(x[t], a);
        mav[i] = make_float2(-2.0f * c1 * x[t], a);
        float rel = x[t] - xmin;
        int bb = min(NBIN - 1, max(0, (int)(rel * inv_bw)));
        atomicAdd(&cnt[bb], 1u);
        atomicAdd(&qs[bb], (int)rintf(rel * 16384.0f));
    }
    __syncthreads();
    for (int u = tid; u < NBIN; u += 256) {
        unsigned int c = cnt[u];
        hcnt[vec * NBIN + u] = (float)c;
        float mu = c ? xmin + ((float)qs[u] / (float)c) * (1.0f / 16384.0f)
                     : xmin + (u + 0.5f) * binw;
        hmu[vec * NBIN + u] = mu;
    }
    if (tid == 0) {
        par[vec * 8 + 0] = xmin;
        par[vec * 8 + 1] = inv_bw;
        par[vec * 8 + 2] = binw;
        par[vec * 8 + 3] = c1;
    }
}

// K2 (fused marg + joint): grid = 96 + 4*4*js blocks, 256 threads.
// bid < 96: marginal windowed histogram sweep (vec = bid>>4, chunk = bid&15).
// bid >= 96: joint brute force, tasks tt=0..3 (b=tt>>1, pr=tt&1 -> vx=b*3, vy=b*3+1+pr),
//            IB=4 i's/thread, LDS-staged j-tile, j-range split js ways.
__global__ void __launch_bounds__(256, 8)
k_main(const float2* __restrict__ xa,
       const float2* __restrict__ ma,
       const float* __restrict__ par,
       const float* __restrict__ hcnt,
       const float* __restrict__ hmu,
       float* __restrict__ marg,
       float* __restrict__ msum_part,
       float* __restrict__ part, int js) {
    __shared__ float4 sj[128];
    const int nib = 4;
    int bid = blockIdx.x;
    int tid = threadIdx.x;

    if (bid < 96) {
        int vec = bid >> 4, ic = bid & 15;
        int i = ic * 256 + tid;
        const float* P = par + vec * 8;
        float xmin = P[0], inv_bw = P[1], c1 = P[3];
        float xi = xa[(size_t)vec * N + i].x;
        float R = sqrtf(45.0f / fabsf(c1));      // exp2 cutoff at 2^-45
        int b0 = max(0, (int)((xi - R - xmin) * inv_bw));
        int b1 = min(NBIN - 1, (int)((xi + R - xmin) * inv_bw) + 1);
        const float* hc = hcnt + vec * NBIN;
        const float* hm = hmu + vec * NBIN;
        float acc = 0.f;
        #pragma unroll 4
        for (int bb = b0; bb <= b1; ++bb) {
            float d = xi - hm[bb];
            acc += hc[bb] * fast_exp2(c1 * d * d);
        }
        float raw = acc * (1.0f / N);
        marg[(size_t)vec * N + i] = raw;
        float tot = block_reduce_sum(raw);
        if (tid == 0) msum_part[bid] = tot;
        return;
    }

    int bid2 = bid - 96;
    int tt = bid2 / (nib * js);
    int rem = bid2 % (nib * js);
    int ib = rem / js, jsp = rem % js;
    int b = tt >> 1, pr = tt & 1;
    int vx = b * 3, vy = b * 3 + 1 + pr;
    int jlen = N / js;
    int j0 = jsp * jlen;
    int ibase = ib * 1024 + tid;

    const float2* xav = xa + (size_t)vx * N;
    const float2* yav = xa + (size_t)vy * N;
    const float2* mxv = ma + (size_t)vx * N;
    const float2* myv = ma + (size_t)vy * N;

    float mx[4], my[4], C[4];
    #pragma unroll
    for (int u = 0; u < 4; ++u) {
        float2 qx = mxv[ibase + u * 256];
        float2 qy = myv[ibase + u * 256];
        mx[u] = qx.x; my[u] = qy.x; C[u] = qx.y + qy.y;
    }
    float acc[4] = {0.f, 0.f, 0.f, 0.f};

    for (int jt = 0; jt < jlen; jt += 128) {
        int cnt = min(128, jlen - jt);
        __syncthreads();
        if (tid < cnt) {
            float2 xq = xav[j0 + jt + tid];
            float2 yq = yav[j0 + jt + tid];
            sj[tid] = make_float4(xq.x, yq.x, xq.y + yq.y, 0.f);
        }
        __syncthreads();
        #pragma unroll 2
        for (int j = 0; j < cnt; j += 2) {
            float4 q0 = sj[j];
            float4 q1 = sj[j + 1];
            float e0[4], e1[4], f0[4], f1[4];
            #pragma unroll
            for (int u = 0; u < 4; ++u) {
                e0[u] = fmaf(my[u], q0.y, fmaf(mx[u], q0.x, C[u])) + q0.z;
                e1[u] = fmaf(my[u], q1.y, fmaf(mx[u], q1.x, C[u])) + q1.z;
            }
            #pragma unroll
            for (int u = 0; u < 4; ++u) {
                f0[u] = fast_exp2(e0[u]);
                f1[u] = fast_exp2(e1[u]);
            }
            #pragma unroll
            for (int u = 0; u < 4; ++u)
                acc[u] += (f0[u] + f1[u]);
        }
    }
    float* dst = part + ((size_t)tt * js + jsp) * N + ibase;
    dst[0]   = acc[0];
    dst[256] = acc[1];
    dst[512] = acc[2];
    dst[768] = acc[3];
}

// K3: reduce joint j-split partials -> pdfj (/N) + per-(task,chunk) sums. 64 blocks.
__global__ void k_reduce(const float* __restrict__ part, float* __restrict__ pdfj,
                         float* __restrict__ jsum_part, int js) {
    int blk = blockIdx.x;
    int tt = blk >> 4;
    int ic = blk & 15;
    int i = ic * 256 + threadIdx.x;
    float s = 0.f;
    #pragma unroll 4
    for (int q = 0; q < js; ++q) s += part[((size_t)tt * js + q) * N + i];
    s *= (1.0f / N);
    pdfj[(size_t)tt * N + i] = s;
    float tot = block_reduce_sum(s);
    if (threadIdx.x == 0) jsum_part[blk] = tot;
}

// K4: fused MI + final. 1 block x 1024 threads.
__global__ void k_mifin(const float* __restrict__ pdfj,
                        const float* __restrict__ jsum_part,
                        const float* __restrict__ marg,
                        const float* __restrict__ msum_part,
                        float* __restrict__ out) {
    __shared__ float tmp[160];
    __shared__ float svec[6], stask[4];
    int tid = threadIdx.x;
    if (tid < 96) tmp[tid] = msum_part[tid];
    else if (tid >= 128 && tid < 192) tmp[96 + tid - 128] = jsum_part[tid - 128];
    __syncthreads();
    if (tid < 6) {
        float s = 0.f;
        #pragma unroll
        for (int q = 0; q < 16; ++q) s += tmp[tid * 16 + q];
        svec[tid] = s;
    } else if (tid >= 8 && tid < 12) {
        int c = tid - 8;
        float s = 0.f;
        #pragma unroll
        for (int q = 0; q < 16; ++q) s += tmp[96 + c * 16 + q];
        stask[c] = s;
    }
    __syncthreads();

    float local = 0.f;
    #pragma unroll
    for (int k = 0; k < 16; ++k) {
        int g = tid + k * 1024;         // 0..16383 over 4 combos x 4096
        int c = g >> 12;
        int i = g & 4095;
        int b = c >> 1, pr = c & 1;
        int vx = b * 3, vy = b * 3 + 1 + pr;
        float pj = pdfj[(size_t)c * N + i] / (stask[c] + 1e-10f);
        float px = marg[(size_t)vx * N + i] / (svec[vx] + 1e-10f);
        float py = marg[(size_t)vy * N + i] / (svec[vy] + 1e-10f);
        float ratio = (pj + 1e-10f) / (px * py + 1e-10f);
        ratio = fminf(fmaxf(ratio, 1e-10f), 1e10f);
        local += pj * __logf(ratio);
    }
    float tot = block_reduce_sum(local);
    if (tid == 0) out[0] = -tot * 0.5f;
}

extern "C" void kernel_launch(void* const* d_in, const int* in_sizes, int n_in,
                              void* d_out, int out_size, void* d_ws, size_t ws_size,
                              hipStream_t stream) {
    const float* fused = (const float*)d_in[0];
    const float* s1    = (const float*)d_in[1];
    const float* s2    = (const float*)d_in[2];
    float* out = (float*)d_out;
    float* ws  = (float*)d_ws;

    // ws layout (floats)
    const size_t off_xa   = 0;                          // 6*N*2
    const size_t off_ma   = off_xa + 12 * (size_t)N;    // 6*N*2
    const size_t off_par  = off_ma + 12 * (size_t)N;    // 64
    const size_t off_hc   = off_par + 64;               // 6*NBIN
    const size_t off_hm   = off_hc + 6 * NBIN;          // 6*NBIN
    const size_t off_mg   = off_hm + 6 * NBIN;          // 6*N
    const size_t off_ms   = off_mg + 6 * (size_t)N;     // 96 (+pad)
    const size_t off_pj   = off_ms + 128;               // 4*N
    const size_t off_js   = off_pj + 4 * (size_t)N;     // 64
    const size_t off_part = off_js + 64;                // 4*js*N

    int js = 32;
    while (js > 1 && (off_part + (size_t)4 * js * N) * 4 > ws_size) js >>= 1;

    float2* ws_xa  = (float2*)(ws + off_xa);
    float2* ws_ma  = (float2*)(ws + off_ma);
    float*  ws_par = ws + off_par;
    float*  ws_hc  = ws + off_hc;
    float*  ws_hm  = ws + off_hm;
    float*  ws_mg  = ws + off_mg;
    float*  ws_ms  = ws + off_ms;
    float*  ws_pj  = ws + off_pj;
    float*  ws_js  = ws + off_js;
    float*  ws_part = ws + off_part;

    k_prep<<<dim3(6), dim3(256), 0, stream>>>(fused, s1, s2, ws_xa, ws_ma,
                                              ws_par, ws_hc, ws_hm);
    k_main<<<dim3(96 + 4 * 4 * js), dim3(256), 0, stream>>>(
        ws_xa, ws_ma, ws_par, ws_hc, ws_hm, ws_mg, ws_ms, ws_part, js);
    k_reduce<<<dim3(64), dim3(256), 0, stream>>>(ws_part, ws_pj, ws_js, js);
    k_mifin<<<dim3(1), dim3(1024), 0, stream>>>(ws_pj, ws_js, ws_mg, ws_ms, out);
}

// Round 9
// 33.024 us; speedup vs baseline: 1.7676x; 1.2230x over previous
//
#include <hip/hip_runtime.h>

#define N 4096
#define NBIN 1024
#define LOG2E 1.4426950408889634f

__device__ __forceinline__ float fast_exp2(float x) {
#if __has_builtin(__builtin_amdgcn_exp2f)
    return __builtin_amdgcn_exp2f(x);
#else
    return exp2f(x);
#endif
}

__device__ float block_reduce_sum(float v) {
    __shared__ float red[16];
    int lane = threadIdx.x & 63;
    int wid = threadIdx.x >> 6;
    #pragma unroll
    for (int off = 32; off; off >>= 1) v += __shfl_down(v, off, 64);
    if (lane == 0) red[wid] = v;
    __syncthreads();
    if (threadIdx.x == 0) {
        int nw = (int)(blockDim.x >> 6);
        float s = red[0];
        for (int w = 1; w < nw; ++w) s += red[w];
        red[0] = s;
    }
    __syncthreads();
    float r = red[0];
    __syncthreads();
    return r;
}

// Combined (sum, sumsq, min, max) single-pass block reduction, 1024 threads.
__device__ float4 block_reduce_stats(float s, float sq, float mn, float mx) {
    __shared__ float4 red4[16];
    int lane = threadIdx.x & 63;
    int wid = threadIdx.x >> 6;
    #pragma unroll
    for (int off = 32; off; off >>= 1) {
        s  += __shfl_down(s, off, 64);
        sq += __shfl_down(sq, off, 64);
        mn  = fminf(mn, __shfl_down(mn, off, 64));
        mx  = fmaxf(mx, __shfl_down(mx, off, 64));
    }
    if (lane == 0) red4[wid] = make_float4(s, sq, mn, mx);
    __syncthreads();
    if (threadIdx.x == 0) {
        float4 r = red4[0];
        #pragma unroll
        for (int w = 1; w < 16; ++w) {
            float4 q = red4[w];
            r.x += q.x; r.y += q.y;
            r.z = fminf(r.z, q.z); r.w = fmaxf(r.w, q.w);
        }
        red4[0] = r;
    }
    __syncthreads();
    float4 r = red4[0];
    __syncthreads();
    return r;
}

// K1: per-vector stats + coefficient arrays + histogram (fused). 6 blocks x 1024.
// xa[vec][j] = (x_j, a_j)   (a = c1*x^2, c1 in log2 units)
// ma[vec][i] = (m_i, a_i)   (m = -2*c1*x)
// par[vec*8 + {0:xmin, 1:inv_binw, 2:binw, 3:c1}]
__global__ void __launch_bounds__(1024)
k_prep(const float* __restrict__ fused,
       const float* __restrict__ s1,
       const float* __restrict__ s2,
       float2* __restrict__ xa,
       float2* __restrict__ ma,
       float* __restrict__ par,
       float* __restrict__ hcnt,
       float* __restrict__ hmu) {
    __shared__ unsigned int cnt[NBIN];
    __shared__ int qs[NBIN];
    int vec = blockIdx.x;
    int b = vec / 3, k = vec % 3;
    const float* src = (k == 0 ? fused : (k == 1 ? s1 : s2)) + b * 16384;
    int tid = threadIdx.x;

    cnt[tid] = 0u; qs[tid] = 0;

    float v[4];
    float s = 0.f, sq = 0.f, mn = 1e30f, mx = -1e30f;
    #pragma unroll
    for (int t = 0; t < 4; ++t) {
        v[t] = src[tid + t * 1024];
        s += v[t]; sq = fmaf(v[t], v[t], sq);
        mn = fminf(mn, v[t]); mx = fmaxf(mx, v[t]);
    }
    float4 r = block_reduce_stats(s, sq, mn, mx);
    float mean = r.x * (1.0f / 4096.0f);
    float tssq = r.y - 4096.0f * mean * mean;       // Σ(v-mean)^2
    float stdv = sqrtf(fmaxf(tssq, 0.f) / 4095.0f); // ddof=1
    float sigma = fminf(fmaxf(0.2f * stdv, 0.001f), 1.0f);
    float inv = 1.0f / (stdv + 1e-8f);
    float c1 = -0.5f * LOG2E / (sigma * sigma);
    float xmin = (r.z - mean) * inv;
    float xmax = (r.w - mean) * inv;
    float range = fmaxf(xmax - xmin, 1e-6f);
    float inv_bw = (float)NBIN / range;
    float binw = range * (1.0f / NBIN);

    float2* xav = xa + (size_t)vec * N;
    float2* mav = ma + (size_t)vec * N;
    __syncthreads();   // cnt/qs zeroed before atomics (also covers reduce reuse)
    #pragma unroll
    for (int t = 0; t < 4; ++t) {
        int i = tid + t * 1024;
        float x = (v[t] - mean) * inv;
        float a = c1 * x * x;
        xav[i] = make_float2(x, a);
        mav[i] = make_float2(-2.0f * c1 * x, a);
        float rel = x - xmin;
        int bb = min(NBIN - 1, max(0, (int)(rel * inv_bw)));
        atomicAdd(&cnt[bb], 1u);
        atomicAdd(&qs[bb], (int)rintf(rel * 16384.0f));
    }
    __syncthreads();
    {
        unsigned int c = cnt[tid];
        hcnt[vec * NBIN + tid] = (float)c;
        float mu = c ? xmin + ((float)qs[tid] / (float)c) * (1.0f / 16384.0f)
                     : xmin + (tid + 0.5f) * binw;
        hmu[vec * NBIN + tid] = mu;
    }
    if (tid == 0) {
        par[vec * 8 + 0] = xmin;
        par[vec * 8 + 1] = inv_bw;
        par[vec * 8 + 2] = binw;
        par[vec * 8 + 3] = c1;
    }
}

// K2 (fused marg + joint): grid = 96 + 4*4*js blocks, 256 threads.
// bid < 96: marginal windowed histogram sweep (vec = bid>>4, chunk = bid&15).
// bid >= 96: joint brute force, tasks tt=0..3 (b=tt>>1, pr=tt&1 -> vx=b*3, vy=b*3+1+pr),
//            IB=4 i's/thread, LDS-staged j-tile, j-range split js ways.
__global__ void __launch_bounds__(256, 8)
k_main(const float2* __restrict__ xa,
       const float2* __restrict__ ma,
       const float* __restrict__ par,
       const float* __restrict__ hcnt,
       const float* __restrict__ hmu,
       float* __restrict__ marg,
       float* __restrict__ msum_part,
       float* __restrict__ part, int js) {
    __shared__ float4 sj[128];
    const int nib = 4;
    int bid = blockIdx.x;
    int tid = threadIdx.x;

    if (bid < 96) {
        int vec = bid >> 4, ic = bid & 15;
        int i = ic * 256 + tid;
        const float* P = par + vec * 8;
        float xmin = P[0], inv_bw = P[1], c1 = P[3];
        float xi = xa[(size_t)vec * N + i].x;
        float R = sqrtf(45.0f / fabsf(c1));      // exp2 cutoff at 2^-45
        int b0 = max(0, (int)((xi - R - xmin) * inv_bw));
        int b1 = min(NBIN - 1, (int)((xi + R - xmin) * inv_bw) + 1);
        const float* hc = hcnt + vec * NBIN;
        const float* hm = hmu + vec * NBIN;
        float acc = 0.f;
        #pragma unroll 4
        for (int bb = b0; bb <= b1; ++bb) {
            float d = xi - hm[bb];
            acc += hc[bb] * fast_exp2(c1 * d * d);
        }
        float raw = acc * (1.0f / N);
        marg[(size_t)vec * N + i] = raw;
        float tot = block_reduce_sum(raw);
        if (tid == 0) msum_part[bid] = tot;
        return;
    }

    int bid2 = bid - 96;
    int tt = bid2 / (nib * js);
    int rem = bid2 % (nib * js);
    int ib = rem / js, jsp = rem % js;
    int b = tt >> 1, pr = tt & 1;
    int vx = b * 3, vy = b * 3 + 1 + pr;
    int jlen = N / js;
    int j0 = jsp * jlen;
    int ibase = ib * 1024 + tid;

    const float2* xav = xa + (size_t)vx * N;
    const float2* yav = xa + (size_t)vy * N;
    const float2* mxv = ma + (size_t)vx * N;
    const float2* myv = ma + (size_t)vy * N;

    float mx[4], my[4], C[4];
    #pragma unroll
    for (int u = 0; u < 4; ++u) {
        float2 qx = mxv[ibase + u * 256];
        float2 qy = myv[ibase + u * 256];
        mx[u] = qx.x; my[u] = qy.x; C[u] = qx.y + qy.y;
    }
    float acc[4] = {0.f, 0.f, 0.f, 0.f};

    for (int jt = 0; jt < jlen; jt += 128) {
        int cnt = min(128, jlen - jt);
        __syncthreads();
        if (tid < cnt) {
            float2 xq = xav[j0 + jt + tid];
            float2 yq = yav[j0 + jt + tid];
            sj[tid] = make_float4(xq.x, yq.x, xq.y + yq.y, 0.f);
        }
        __syncthreads();
        #pragma unroll 2
        for (int j = 0; j < cnt; j += 2) {
            float4 q0 = sj[j];
            float4 q1 = sj[j + 1];
            float e0[4], e1[4], f0[4], f1[4];
            #pragma unroll
            for (int u = 0; u < 4; ++u) {
                e0[u] = fmaf(my[u], q0.y, fmaf(mx[u], q0.x, C[u])) + q0.z;
                e1[u] = fmaf(my[u], q1.y, fmaf(mx[u], q1.x, C[u])) + q1.z;
            }
            #pragma unroll
            for (int u = 0; u < 4; ++u) {
                f0[u] = fast_exp2(e0[u]);
                f1[u] = fast_exp2(e1[u]);
            }
            #pragma unroll
            for (int u = 0; u < 4; ++u)
                acc[u] += (f0[u] + f1[u]);
        }
    }
    float* dst = part + ((size_t)tt * js + jsp) * N + ibase;
    dst[0]   = acc[0];
    dst[256] = acc[1];
    dst[512] = acc[2];
    dst[768] = acc[3];
}

// K3: reduce joint j-split partials -> rawj, then per-chunk MI numerator
// A = Σ rawj*log(rawj/(rawx*rawy)) and Sj partials. 64 blocks x 256.
__global__ void k_reduce(const float* __restrict__ part,
                         const float* __restrict__ marg,
                         float* __restrict__ A_part,
                         float* __restrict__ jsum_part, int js) {
    int blk = blockIdx.x;
    int tt = blk >> 4;
    int ic = blk & 15;
    int b = tt >> 1, pr = tt & 1;
    int vx = b * 3, vy = b * 3 + 1 + pr;
    int i = ic * 256 + threadIdx.x;
    float s = 0.f;
    #pragma unroll 4
    for (int q = 0; q < js; ++q) s += part[((size_t)tt * js + q) * N + i];
    s *= (1.0f / N);
    float rx = marg[(size_t)vx * N + i];
    float ry = marg[(size_t)vy * N + i];
    float a = s * __logf(s / (rx * ry));
    // two block reductions (sequential, reuses the same LDS safely)
    float stot = block_reduce_sum(s);
    float atot = block_reduce_sum(a);
    if (threadIdx.x == 0) {
        jsum_part[blk] = stot;
        A_part[blk] = atot;
    }
}

// K4: final. 1 block x 128 threads.
// MI_c = A_c/Sj_c + log(Sx*Sy/Sj_c); out = -(ΣMI)/2.
__global__ void k_fin(const float* __restrict__ A_part,
                      const float* __restrict__ jsum_part,
                      const float* __restrict__ msum_part,
                      float* __restrict__ out) {
    __shared__ float svec[6], stask[4], sA[4];
    int tid = threadIdx.x;
    if (tid < 6) {
        float s = 0.f;
        #pragma unroll
        for (int q = 0; q < 16; ++q) s += msum_part[tid * 16 + q];
        svec[tid] = s;
    } else if (tid >= 8 && tid < 12) {
        int c = tid - 8;
        float s = 0.f, a = 0.f;
        #pragma unroll
        for (int q = 0; q < 16; ++q) {
            s += jsum_part[c * 16 + q];
            a += A_part[c * 16 + q];
        }
        stask[c] = s;
        sA[c] = a;
    }
    __syncthreads();
    if (tid == 0) {
        float mi = 0.f;
        #pragma unroll
        for (int c = 0; c < 4; ++c) {
            int b = c >> 1, pr = c & 1;
            int vx = b * 3, vy = b * 3 + 1 + pr;
            mi += sA[c] / stask[c] + __logf(svec[vx] * svec[vy] / stask[c]);
        }
        out[0] = -mi * 0.5f;
    }
}

extern "C" void kernel_launch(void* const* d_in, const int* in_sizes, int n_in,
                              void* d_out, int out_size, void* d_ws, size_t ws_size,
                              hipStream_t stream) {
    const float* fused = (const float*)d_in[0];
    const float* s1    = (const float*)d_in[1];
    const float* s2    = (const float*)d_in[2];
    float* out = (float*)d_out;
    float* ws  = (float*)d_ws;

    // ws layout (floats)
    const size_t off_xa   = 0;                          // 6*N*2
    const size_t off_ma   = off_xa + 12 * (size_t)N;    // 6*N*2
    const size_t off_par  = off_ma + 12 * (size_t)N;    // 64
    const size_t off_hc   = off_par + 64;               // 6*NBIN
    const size_t off_hm   = off_hc + 6 * NBIN;          // 6*NBIN
    const size_t off_mg   = off_hm + 6 * NBIN;          // 6*N
    const size_t off_ms   = off_mg + 6 * (size_t)N;     // 96 (+pad)
    const size_t off_A    = off_ms + 128;               // 64
    const size_t off_js   = off_A + 64;                 // 64
    const size_t off_part = off_js + 64;                // 4*js*N

    int js = 32;
    while (js > 1 && (off_part + (size_t)4 * js * N) * 4 > ws_size) js >>= 1;

    float2* ws_xa  = (float2*)(ws + off_xa);
    float2* ws_ma  = (float2*)(ws + off_ma);
    float*  ws_par = ws + off_par;
    float*  ws_hc  = ws + off_hc;
    float*  ws_hm  = ws + off_hm;
    float*  ws_mg  = ws + off_mg;
    float*  ws_ms  = ws + off_ms;
    float*  ws_A   = ws + off_A;
    float*  ws_js  = ws + off_js;
    float*  ws_part = ws + off_part;

    k_prep<<<dim3(6), dim3(1024), 0, stream>>>(fused, s1, s2, ws_xa, ws_ma,
                                               ws_par, ws_hc, ws_hm);
    k_main<<<dim3(96 + 4 * 4 * js), dim3(256), 0, stream>>>(
        ws_xa, ws_ma, ws_par, ws_hc, ws_hm, ws_mg, ws_ms, ws_part, js);
    k_reduce<<<dim3(64), dim3(256), 0, stream>>>(ws_part, ws_mg, ws_A, ws_js, js);
    k_fin<<<dim3(1), dim3(128), 0, stream>>>(ws_A, ws_js, ws_ms, out);
}